// Round 1
// baseline (2191.620 us; speedup 1.0000x reference)
//
#include <hip/hip_runtime.h>

#define DIM 384
#define HALFC 256   // 2*H boundary: cols [0,256) from incoming (idx[:,1]), [256,384) from outgoing (idx[:,0])
#define C4PER 96    // 384/4 float4s per row

// Step 1: per-edge global node indices + degree counts.
__global__ void build_idx_kernel(const int* __restrict__ org, const int* __restrict__ ptr,
                                 const int* __restrict__ lg, int B, int E,
                                 int* __restrict__ gidx,
                                 int* __restrict__ cnt_in, int* __restrict__ cnt_out) {
    int e = blockIdx.x * blockDim.x + threadIdx.x;
    if (e >= E) return;
    // offset for the graph containing edge e: sum of org sizes of preceding graphs
    int off = 0;
    for (int j = 0; j < B; ++j) {
        // ptr[j+1] is a uniform address per j -> broadcast load from cache
        if (e >= ptr[j + 1]) off += org[j];
    }
    int n_out = lg[2 * e]     + off;  // idx[:,0]
    int n_in  = lg[2 * e + 1] + off;  // idx[:,1]
    gidx[2 * e]     = n_out;
    gidx[2 * e + 1] = n_in;
    atomicAdd(&cnt_out[n_out], 1);
    atomicAdd(&cnt_in[n_in], 1);
}

// Step 2: inverse counts (clamped to 1, matching scatter-mean semantics)
__global__ void inv_counts_kernel(const int* __restrict__ cnt, float* __restrict__ inv, int n) {
    int i = blockIdx.x * blockDim.x + threadIdx.x;
    if (i < n) inv[i] = 1.0f / (float)max(cnt[i], 1);
}

// Step 3: single-pass scaled scatter. One thread per float4 of x.
__global__ void scatter_kernel(const float4* __restrict__ x4, const int* __restrict__ gidx,
                               const float* __restrict__ inv_in, const float* __restrict__ inv_out,
                               float* __restrict__ out, int total) {
    int i = blockIdx.x * blockDim.x + threadIdx.x;
    if (i >= total) return;
    int e  = i / C4PER;
    int c4 = i - e * C4PER;
    int col = c4 * 4;
    int node;
    float inv;
    if (col < HALFC) {
        node = gidx[2 * e + 1];      // incoming target
        inv  = inv_in[node];
    } else {
        node = gidx[2 * e];          // outgoing target
        inv  = inv_out[node];
    }
    float4 v = x4[(long)e * C4PER + c4];
    float* o = out + (long)node * DIM + col;
    unsafeAtomicAdd(o + 0, v.x * inv);
    unsafeAtomicAdd(o + 1, v.y * inv);
    unsafeAtomicAdd(o + 2, v.z * inv);
    unsafeAtomicAdd(o + 3, v.w * inv);
}

extern "C" void kernel_launch(void* const* d_in, const int* in_sizes, int n_in,
                              void* d_out, int out_size, void* d_ws, size_t ws_size,
                              hipStream_t stream) {
    const float* x  = (const float*)d_in[0];
    const int* org  = (const int*)d_in[1];
    const int* ptr  = (const int*)d_in[2];
    const int* lg   = (const int*)d_in[3];

    int B = in_sizes[1];          // 16
    int E = in_sizes[3] / 2;      // 320000
    int TN = out_size / DIM;      // total nodes = 160000
    float* out = (float*)d_out;

    // ws layout: [cnt_in | cnt_out] (2*TN int) | [inv_in | inv_out] (2*TN float) | gidx (2*E int)
    char* ws = (char*)d_ws;
    int*   cnt  = (int*)ws;
    float* inv  = (float*)(ws + (size_t)2 * TN * sizeof(int));
    int*   gidx = (int*)(ws + (size_t)4 * TN * sizeof(int));

    hipMemsetAsync(d_out, 0, (size_t)out_size * sizeof(float), stream);
    hipMemsetAsync(cnt, 0, (size_t)2 * TN * sizeof(int), stream);

    build_idx_kernel<<<(E + 255) / 256, 256, 0, stream>>>(org, ptr, lg, B, E,
                                                          gidx, cnt, cnt + TN);

    int n2 = 2 * TN;
    inv_counts_kernel<<<(n2 + 255) / 256, 256, 0, stream>>>(cnt, inv, n2);

    int total = E * C4PER;  // 30.72M float4s
    scatter_kernel<<<(total + 255) / 256, 256, 0, stream>>>((const float4*)x, gidx,
                                                            inv, inv + TN, out, total);
}

// Round 2
// 802.937 us; speedup vs baseline: 2.7295x; 2.7295x over previous
//
#include <hip/hip_runtime.h>

#define DIM 384
#define HALFC 256   // cols [0,256) from incoming (lg[2e+1]), [256,384) from outgoing (lg[2e])
#define C4PER 96    // 384/4 float4s per row

#define SCAN_BLOCK 256
#define SCAN_ITEMS 8
#define SCAN_CHUNK (SCAN_BLOCK * SCAN_ITEMS)  // 2048

// Per-edge: resolve global node ids, bump degree counts.
// cnt[0..TN)   = in-degree  (keyed by lg[2e+1]+off) -> serves cols [0,256)
// cnt[TN..2TN) = out-degree (keyed by lg[2e]+off)   -> serves cols [256,384)
__global__ void count_kernel(const int* __restrict__ org, const int* __restrict__ ptr,
                             const int* __restrict__ lg, int B, int E, int TN,
                             int* __restrict__ cnt) {
    int e = blockIdx.x * blockDim.x + threadIdx.x;
    if (e >= E) return;
    int off = 0;
    for (int j = 0; j < B; ++j)
        if (e >= ptr[j + 1]) off += org[j];   // uniform addrs -> broadcast loads
    int n_out = lg[2 * e]     + off;
    int n_in  = lg[2 * e + 1] + off;
    atomicAdd(&cnt[n_in], 1);
    atomicAdd(&cnt[TN + n_out], 1);
}

// Exclusive scan, stage 1: per-block (2048 elems) partial scan + block sums.
__global__ void scan1_kernel(const int* __restrict__ cnt, int* __restrict__ offs,
                             int* __restrict__ bsum, int n) {
    __shared__ int s[SCAN_BLOCK];
    int base = blockIdx.x * SCAN_CHUNK;
    int tid = threadIdx.x;
    int v[SCAN_ITEMS];
    int tsum = 0;
#pragma unroll
    for (int j = 0; j < SCAN_ITEMS; ++j) {
        int i = base + tid * SCAN_ITEMS + j;
        v[j] = (i < n) ? cnt[i] : 0;
        tsum += v[j];
    }
    s[tid] = tsum;
    __syncthreads();
    for (int d = 1; d < SCAN_BLOCK; d <<= 1) {
        int t = (tid >= d) ? s[tid - d] : 0;
        __syncthreads();
        s[tid] += t;
        __syncthreads();
    }
    if (tid == SCAN_BLOCK - 1) bsum[blockIdx.x] = s[SCAN_BLOCK - 1];
    int run = (tid > 0) ? s[tid - 1] : 0;
#pragma unroll
    for (int j = 0; j < SCAN_ITEMS; ++j) {
        int i = base + tid * SCAN_ITEMS + j;
        if (i < n) offs[i] = run;
        run += v[j];
    }
}

// Stage 2: exclusive scan of block sums in place (single block, nb up to a few hundred).
__global__ void scan2_kernel(int* __restrict__ bsum, int nb) {
    __shared__ int s[SCAN_BLOCK];
    int tid = threadIdx.x;
    int carry = 0;
    for (int base = 0; base < nb; base += SCAN_BLOCK) {
        int i = base + tid;
        s[tid] = (i < nb) ? bsum[i] : 0;
        __syncthreads();
        for (int d = 1; d < SCAN_BLOCK; d <<= 1) {
            int t = (tid >= d) ? s[tid - d] : 0;
            __syncthreads();
            s[tid] += t;
            __syncthreads();
        }
        int excl = carry + ((tid > 0) ? s[tid - 1] : 0);
        if (i < nb) bsum[i] = excl;
        carry += s[SCAN_BLOCK - 1];
        __syncthreads();
    }
}

// Stage 3: add scanned block sums back.
__global__ void scan3_kernel(int* __restrict__ offs, const int* __restrict__ bsum, int n) {
    int i = blockIdx.x * blockDim.x + threadIdx.x;
    if (i < n) offs[i] += bsum[i / SCAN_CHUNK];
}

// Fill CSR edge lists. Advances offs via atomicAdd: afterwards offs[slot] == segment END.
__global__ void fill_kernel(const int* __restrict__ org, const int* __restrict__ ptr,
                            const int* __restrict__ lg, int B, int E, int TN,
                            int* __restrict__ offs, int* __restrict__ list) {
    int e = blockIdx.x * blockDim.x + threadIdx.x;
    if (e >= E) return;
    int off = 0;
    for (int j = 0; j < B; ++j)
        if (e >= ptr[j + 1]) off += org[j];
    int n_out = lg[2 * e]     + off;
    int n_in  = lg[2 * e + 1] + off;
    int p = atomicAdd(&offs[n_in], 1);
    list[p] = e;
    int q = atomicAdd(&offs[TN + n_out], 1);
    list[q] = e;
}

// Gather-mean: one thread per output float4. Reads each x element exactly once.
__global__ void gather_kernel(const float4* __restrict__ x4,
                              const int* __restrict__ cnt, const int* __restrict__ offs_end,
                              const int* __restrict__ list,
                              float4* __restrict__ out4, int TN, int total) {
    int i = blockIdx.x * blockDim.x + threadIdx.x;
    if (i >= total) return;
    int node = i / C4PER;
    int c4 = i - node * C4PER;
    int slot = (c4 * 4 < HALFC) ? node : TN + node;
    int deg = cnt[slot];
    int end = offs_end[slot];
    int start = end - deg;
    float4 acc = {0.f, 0.f, 0.f, 0.f};
    for (int k = start; k < end; ++k) {
        int e = list[k];
        float4 v = x4[(long)e * C4PER + c4];
        acc.x += v.x; acc.y += v.y; acc.z += v.z; acc.w += v.w;
    }
    float inv = 1.0f / (float)max(deg, 1);
    acc.x *= inv; acc.y *= inv; acc.z *= inv; acc.w *= inv;
    out4[i] = acc;
}

extern "C" void kernel_launch(void* const* d_in, const int* in_sizes, int n_in,
                              void* d_out, int out_size, void* d_ws, size_t ws_size,
                              hipStream_t stream) {
    const float* x = (const float*)d_in[0];
    const int* org = (const int*)d_in[1];
    const int* ptr = (const int*)d_in[2];
    const int* lg  = (const int*)d_in[3];

    int B  = in_sizes[1];       // 16
    int E  = in_sizes[3] / 2;   // 320000
    int TN = out_size / DIM;    // 160000 total nodes
    int n2 = 2 * TN;

    // ws layout (ints): cnt[2*TN] | offs[2*TN] | bsum[1024] | list[2*E]
    int* cnt  = (int*)d_ws;
    int* offs = cnt + n2;
    int* bsum = offs + n2;
    int* list = bsum + 1024;

    hipMemsetAsync(cnt, 0, (size_t)n2 * sizeof(int), stream);

    count_kernel<<<(E + 255) / 256, 256, 0, stream>>>(org, ptr, lg, B, E, TN, cnt);

    int nb = (n2 + SCAN_CHUNK - 1) / SCAN_CHUNK;
    scan1_kernel<<<nb, SCAN_BLOCK, 0, stream>>>(cnt, offs, bsum, n2);
    scan2_kernel<<<1, SCAN_BLOCK, 0, stream>>>(bsum, nb);
    scan3_kernel<<<(n2 + 255) / 256, 256, 0, stream>>>(offs, bsum, n2);

    fill_kernel<<<(E + 255) / 256, 256, 0, stream>>>(org, ptr, lg, B, E, TN, offs, list);

    int total = TN * C4PER;  // 15.36M output float4s
    gather_kernel<<<(total + 255) / 256, 256, 0, stream>>>((const float4*)x, cnt, offs, list,
                                                           (float4*)d_out, TN, total);
}